// Round 14
// baseline (264.663 us; speedup 1.0000x reference)
//
#include <hip/hip_runtime.h>
#include <hip/hip_fp16.h>

#define N_NODES 100000
#define T_P 12
#define C_H 32
#define E_EDGES 3200000

#define NODES_PER_B 128
#define NB 782                    // ceil(100000/128) fine bins
#define CAPA 4608                 // slot capacity per bin = 9*512 (mean 4092, +8σ)

#define VEC_E (E_EDGES / 4)       // 800000 int4/float4 vectors
#define P1_THREADS 512
#define P1_VECS 2048              // vectors per window => 8192 edges
#define NBLK1 ((VEC_E + P1_VECS - 1) / P1_VECS)   // 391

// ws layout (4-byte units from d_ws):
//   P[256] | cursor[NB] | pad | y_fp16[N*16 halves] | entries[NB*CAPA]{float2}  ~32 MB

// Phase 1: fine scatter (128-node bins). Two-pass over the window, but dst is
// kept in registers (single dst read). Rank comes from the counting atomic's
// return; one claim ret-atomic per (window,bin) (~306K total).
// Record: {src(17b) | dl7<<17, w_fp32}.
__global__ void __launch_bounds__(512)
bucket_scatter_kernel(const int* __restrict__ src, const int* __restrict__ dst,
                      const float* __restrict__ w, int* __restrict__ cursor,
                      float2* __restrict__ entries) {
    __shared__ int h[NB];
    __shared__ int claim[NB];
    int tid = threadIdx.x;
    int vbase = blockIdx.x * P1_VECS;
    for (int i = tid; i < NB; i += 512) h[i] = 0;
    __syncthreads();
    const int4* d4 = (const int4*)dst;
    int4 dc[4];
    int rra[16];
#pragma unroll
    for (int q = 0; q < 4; ++q) {
        int v = vbase + q * 512 + tid;
        if (v < VEC_E) {
            int4 d = d4[v];
            dc[q] = d;
            rra[q * 4 + 0] = atomicAdd(&h[d.x >> 7], 1);
            rra[q * 4 + 1] = atomicAdd(&h[d.y >> 7], 1);
            rra[q * 4 + 2] = atomicAdd(&h[d.z >> 7], 1);
            rra[q * 4 + 3] = atomicAdd(&h[d.w >> 7], 1);
        }
    }
    __syncthreads();
    for (int i = tid; i < NB; i += 512) {
        int c = h[i];
        claim[i] = c ? atomicAdd(&cursor[i], c) : 0;
    }
    __syncthreads();
    const int4* s4 = (const int4*)src;
    const float4* w4 = (const float4*)w;
#pragma unroll
    for (int q = 0; q < 4; ++q) {
        int v = vbase + q * 512 + tid;
        if (v < VEC_E) {
            int4 d = dc[q];
            int4 s = s4[v];
            float4 ww = w4[v];
            int bin, dl, pos;
            bin = d.x >> 7; dl = d.x & 127; pos = claim[bin] + rra[q * 4 + 0];
            if (pos < CAPA) entries[(size_t)bin * CAPA + pos] = make_float2(__int_as_float(s.x | (dl << 17)), ww.x);
            bin = d.y >> 7; dl = d.y & 127; pos = claim[bin] + rra[q * 4 + 1];
            if (pos < CAPA) entries[(size_t)bin * CAPA + pos] = make_float2(__int_as_float(s.y | (dl << 17)), ww.y);
            bin = d.z >> 7; dl = d.z & 127; pos = claim[bin] + rra[q * 4 + 2];
            if (pos < CAPA) entries[(size_t)bin * CAPA + pos] = make_float2(__int_as_float(s.z | (dl << 17)), ww.z);
            bin = d.w >> 7; dl = d.w & 127; pos = claim[bin] + rra[q * 4 + 3];
            if (pos < CAPA) entries[(size_t)bin * CAPA + pos] = make_float2(__int_as_float(s.w | (dl << 17)), ww.w);
        }
    }
}

// Phase 2: per-bin degree + fp16 y rows (32B). Block 0 additionally computes
// the derived gate params P (folds the old params_kernel launch away).
__global__ void __launch_bounds__(512)
prep_kernel(const float2* __restrict__ entries, const int* __restrict__ cursor,
            const float* __restrict__ x, __half* __restrict__ y,
            const float* __restrict__ wz, const float* __restrict__ bz,
            const float* __restrict__ wh, const float* __restrict__ bh,
            const float* __restrict__ lwz, const float* __restrict__ lbz,
            const float* __restrict__ lwh, const float* __restrict__ lbh,
            const float* __restrict__ att, float* __restrict__ P) {
    __shared__ float wsum[NODES_PER_B];
    __shared__ float dloc[NODES_PER_B];
    int tid = threadIdx.x;
    int b = blockIdx.x;
    int nbase = b << 7;
    size_t lo = (size_t)b * CAPA;
    int ne = cursor[b]; if (ne > CAPA) ne = CAPA;
    if (tid < NODES_PER_B) wsum[tid] = 0.f;
    __syncthreads();
    for (int k = tid; k < ne; k += 512) {
        float2 e = entries[lo + k];
        atomicAdd(&wsum[(__float_as_int(e.x) >> 17) & 127], e.y);
    }
    __syncthreads();
    if (tid < NODES_PER_B) {
        int n = nbase + tid;
        dloc[tid] = (n < N_NODES) ? rsqrtf(1.0f + wsum[tid]) : 0.f;
    }
    __syncthreads();
    if (tid < 256) {
        int nl = tid >> 1, q = tid & 1;
        int n = nbase + nl;
        if (n < N_NODES) {
            float di = dloc[nl];
            union { __half h[8]; float4 f4; } u;
            if (q == 0) {
                float4 a = ((const float4*)x)[(size_t)n * 3 + 0];
                float4 c = ((const float4*)x)[(size_t)n * 3 + 1];
                u.h[0] = __float2half_rn(a.x * di); u.h[1] = __float2half_rn(a.y * di);
                u.h[2] = __float2half_rn(a.z * di); u.h[3] = __float2half_rn(a.w * di);
                u.h[4] = __float2half_rn(c.x * di); u.h[5] = __float2half_rn(c.y * di);
                u.h[6] = __float2half_rn(c.z * di); u.h[7] = __float2half_rn(c.w * di);
            } else {
                float4 c = ((const float4*)x)[(size_t)n * 3 + 2];
                u.h[0] = __float2half_rn(c.x * di); u.h[1] = __float2half_rn(c.y * di);
                u.h[2] = __float2half_rn(c.z * di); u.h[3] = __float2half_rn(c.w * di);
                u.h[4] = __ushort_as_half((unsigned short)0);
                u.h[5] = __ushort_as_half((unsigned short)0);
                u.h[6] = __ushort_as_half((unsigned short)0);
                u.h[7] = __ushort_as_half((unsigned short)0);
            }
            ((float4*)y)[((size_t)n << 1) + q] = u.f4;
        }
    }
    if (b == 0) {
        int o = tid;
        if (o < C_H) {
            float az = 0.f, bzv = 0.f, ah = 0.f, bhv = 0.f;
            for (int c = 0; c < C_H; ++c) {
                float lz = lwz[o * 2 * C_H + c];
                float lh = lwh[o * 2 * C_H + c];
                az += wz[c] * lz;  bzv += bz[c] * lz;
                ah += wh[c] * lh;  bhv += bh[c] * lh;
            }
            P[16 + o]  = az;  P[48 + o]  = bzv + lbz[o];
            P[80 + o]  = ah;  P[112 + o] = bhv + lbh[o];
        }
        if (o == 0) {
            float m = -1e30f;
            for (int t = 0; t < T_P; ++t) m = fmaxf(m, att[t]);
            float e[T_P], s = 0.f;
            for (int t = 0; t < T_P; ++t) { e[t] = __expf(att[t] - m); s += e[t]; }
            float inv = 1.0f / s;
            for (int t = 0; t < T_P; ++t) P[t] = e[t] * inv;
        }
    }
}

// Phase 3: per fine bin (128 nodes): register-staged counting sort (stage holds
// COMPRESSED 4B records {src17 | w_fp15<<17} — dl becomes positional after the
// sort; w>0 so the fp16 sign bit is droppable) + wsum->dinv in the same pass +
// 4-lane-per-node gather on the L2-resident fp16 y-table + gate/attn/head.
// ~21KB LDS, 512 thr -> 4 blocks/CU = 32 waves/CU; 782 blocks = 3.05/CU.
__global__ void __launch_bounds__(512, 8)
sort_gather_kernel(const float2* __restrict__ entries, const int* __restrict__ cursor,
                   const __half* __restrict__ y, const float* __restrict__ P,
                   const float* __restrict__ head_w, const float* __restrict__ head_b,
                   float* __restrict__ out) {
    __shared__ unsigned int stage[CAPA];        // 18.4 KB, node-sorted 4B records
    __shared__ int   cnt[NODES_PER_B];
    __shared__ int   inc[NODES_PER_B];          // inclusive prefix
    __shared__ float wsum[NODES_PER_B];
    __shared__ float dloc[NODES_PER_B];
    __shared__ float Ps[160];
    __shared__ float hws[C_H];
    int tid = threadIdx.x;
    int b = blockIdx.x;
    size_t lo = (size_t)b * CAPA;
    int ne = cursor[b]; if (ne > CAPA) ne = CAPA;
    if (tid < 160) Ps[tid] = P[tid];
    if (tid < C_H) hws[tid] = head_w[tid];
    if (tid < NODES_PER_B) { cnt[tid] = 0; wsum[tid] = 0.f; }
    __syncthreads();
    float2 ent[9];
    int    rr[9];
#pragma unroll
    for (int i = 0; i < 9; ++i) {
        int k = tid + i * 512;
        if (k < ne) {
            float2 e = entries[lo + k];
            ent[i] = e;
            int dl = (__float_as_int(e.x) >> 17) & 127;
            rr[i] = atomicAdd(&cnt[dl], 1);
            atomicAdd(&wsum[dl], e.y);
        }
    }
    __syncthreads();
    if (tid < NODES_PER_B) inc[tid] = cnt[tid];
    __syncthreads();
    for (int d = 1; d < NODES_PER_B; d <<= 1) {
        int t = (tid >= d && tid < NODES_PER_B) ? inc[tid - d] : 0;
        __syncthreads();
        if (tid < NODES_PER_B) inc[tid] += t;
        __syncthreads();
    }
    if (tid < NODES_PER_B) dloc[tid] = rsqrtf(1.0f + wsum[tid]);
#pragma unroll
    for (int i = 0; i < 9; ++i) {
        int k = tid + i * 512;
        if (k < ne) {
            int u = __float_as_int(ent[i].x);
            int dl = (u >> 17) & 127;
            unsigned int hb = (unsigned int)__half_as_ushort(__float2half_rn(ent[i].y));
            stage[inc[dl] - cnt[dl] + rr[i]] = (unsigned int)(u & 0x1FFFF) | (hb << 17);
        }
    }
    __syncthreads();
    // ---- gather: 4 lanes per node; edges from LDS, fp16 y rows from L2 ----
    int nl = tid >> 2, lane = tid & 3;
    int n = (b << 7) + nl;
    if (n >= N_NODES) return;                   // no barriers below
    int end = inc[nl];
    int start = end - cnt[nl];
    float4 a0 = make_float4(0.f, 0.f, 0.f, 0.f);
    float4 a1 = a0, a2 = a0;
    if (lane == 0) {                            // self term, added once
        const float4* yn = (const float4*)(y + ((size_t)n << 4));
        float4 r0 = yn[0], r1 = yn[1];
        const __half2* hp = (const __half2*)&r0;
        const __half2* hq = (const __half2*)&r1;
        float2 p0 = __half22float2(hp[0]), p1 = __half22float2(hp[1]);
        float2 p2 = __half22float2(hp[2]), p3 = __half22float2(hp[3]);
        float2 p4 = __half22float2(hq[0]), p5 = __half22float2(hq[1]);
        a0 = make_float4(p0.x, p0.y, p1.x, p1.y);
        a1 = make_float4(p2.x, p2.y, p3.x, p3.y);
        a2 = make_float4(p4.x, p4.y, p5.x, p5.y);
    }
    for (int j = start + lane; j < end; j += 4) {
        unsigned int rec = stage[j];
        int s = rec & 0x1FFFF;
        float c = __half2float(__ushort_as_half((unsigned short)(rec >> 17)));
        const float4* ys = (const float4*)(y + ((size_t)s << 4));  // one 64B line
        float4 r0 = ys[0], r1 = ys[1];
        const __half2* hp = (const __half2*)&r0;
        const __half2* hq = (const __half2*)&r1;
        float2 p0 = __half22float2(hp[0]), p1 = __half22float2(hp[1]);
        float2 p2 = __half22float2(hp[2]), p3 = __half22float2(hp[3]);
        float2 p4 = __half22float2(hq[0]), p5 = __half22float2(hq[1]);
        a0.x += c * p0.x; a0.y += c * p0.y; a0.z += c * p1.x; a0.w += c * p1.y;
        a1.x += c * p2.x; a1.y += c * p2.y; a1.z += c * p3.x; a1.w += c * p3.y;
        a2.x += c * p4.x; a2.y += c * p4.y; a2.z += c * p5.x; a2.w += c * p5.y;
    }
#define RED4(v) v += __shfl_xor(v, 1); v += __shfl_xor(v, 2)
    RED4(a0.x); RED4(a0.y); RED4(a0.z); RED4(a0.w);
    RED4(a1.x); RED4(a1.y); RED4(a1.z); RED4(a1.w);
    RED4(a2.x); RED4(a2.y); RED4(a2.z); RED4(a2.w);
#undef RED4
    float din = dloc[nl];
    float av[T_P];
    av[0] = a0.x * din; av[1] = a0.y * din; av[2]  = a0.z * din; av[3]  = a0.w * din;
    av[4] = a1.x * din; av[5] = a1.y * din; av[6]  = a1.z * din; av[7]  = a1.w * din;
    av[8] = a2.x * din; av[9] = a2.y * din; av[10] = a2.z * din; av[11] = a2.w * din;
    float acc = 0.f;
#pragma unroll
    for (int k = 0; k < 8; ++k) {
        int c = (lane << 3) + k;
        float Az = Ps[16 + c], Bz = Ps[48 + c], Ah = Ps[80 + c], Bh = Ps[112 + c];
        float hc = 0.f;
#pragma unroll
        for (int t = 0; t < T_P; ++t) {
            float a = av[t];
            float oz = 1.f / (1.f + __expf(a * Az + Bz));      // 1 - sigmoid(u)
            float vv = a * Ah + Bh;
            float th = 1.f - 2.f / (1.f + __expf(2.f * vv));   // tanh
            hc += Ps[t] * oz * th;
        }
        acc += fmaxf(hc, 0.f) * hws[c];
    }
    acc += __shfl_xor(acc, 1);
    acc += __shfl_xor(acc, 2);
    if (lane == 0) out[n] = acc + head_b[0];
}

extern "C" void kernel_launch(void* const* d_in, const int* in_sizes, int n_in,
                              void* d_out, int out_size, void* d_ws, size_t ws_size,
                              hipStream_t stream) {
    const float* x    = (const float*)d_in[0];
    const int*   ei   = (const int*)d_in[1];      // [2, E]: src = ei, dst = ei + E
    const float* ew   = (const float*)d_in[2];
    const float* w_z  = (const float*)d_in[3];
    const float* b_z  = (const float*)d_in[4];
    const float* w_h  = (const float*)d_in[7];
    const float* b_h  = (const float*)d_in[8];
    const float* lw_z = (const float*)d_in[9];
    const float* lb_z = (const float*)d_in[10];
    const float* lw_h = (const float*)d_in[13];
    const float* lb_h = (const float*)d_in[14];
    const float* att  = (const float*)d_in[15];
    const float* hw   = (const float*)d_in[16];
    const float* hb   = (const float*)d_in[17];
    float* out = (float*)d_out;

    float* wsf      = (float*)d_ws;
    float* P        = wsf;                          // 256           @0
    int*   cursor   = (int*)(wsf + 256);            // NB            @256
    __half* y       = (__half*)(wsf + 1040);        // N*16 halves (32B rows)
    float2* entries = (float2*)(wsf + 1040 + (size_t)N_NODES * 8);  // NB*CAPA

    const int* srcp = ei;
    const int* dstp = ei + E_EDGES;

    hipMemsetAsync(cursor, 0, NB * sizeof(int), stream);
    bucket_scatter_kernel<<<NBLK1, P1_THREADS, 0, stream>>>(srcp, dstp, ew, cursor, entries);
    prep_kernel<<<NB, 512, 0, stream>>>(entries, cursor, x, y,
                                        w_z, b_z, w_h, b_h, lw_z, lb_z, lw_h, lb_h, att, P);
    sort_gather_kernel<<<NB, 512, 0, stream>>>(entries, cursor, y, P, hw, hb, out);
}

// Round 16
// 237.414 us; speedup vs baseline: 1.1148x; 1.1148x over previous
//
#include <hip/hip_runtime.h>
#include <hip/hip_fp16.h>

#define N_NODES 100000
#define T_P 12
#define C_H 32
#define E_EDGES 3200000

#define NODES_PER_B 256
#define NB 391                    // ceil(100000/256) coarse bins
#define CAPA 8704                 // slot capacity per bin (mean 8184, sd ~90, +5.8σ)

#define VEC_E (E_EDGES / 4)       // 800000 int4/float4 vectors
#define P1_THREADS 512
#define P1_VECS 2048              // vectors per window => 8192 edges
#define NBLK1 ((VEC_E + P1_VECS - 1) / P1_VECS)   // 391

// ws layout (4-byte units from d_ws):
//   P[256] | dinv[N] | cursor[NB] | pad | y_fp16[N*16 halves] | entries[NB*CAPA]{float2}

// Phase 1: COARSE scatter (256-node bins). Two passes over the window but dst
// is kept in registers (single dst read). Rank = counting atomic's return;
// one claim ret-atomic per (window,bin) (~153K). Record: {src17 | dl8<<17, w}.
__global__ void __launch_bounds__(512)
bucket_scatter_kernel(const int* __restrict__ src, const int* __restrict__ dst,
                      const float* __restrict__ w, int* __restrict__ cursor,
                      float2* __restrict__ entries) {
    __shared__ int h[NB];
    __shared__ int claim[NB];
    int tid = threadIdx.x;
    int vbase = blockIdx.x * P1_VECS;
    for (int i = tid; i < NB; i += 512) h[i] = 0;
    __syncthreads();
    const int4* d4 = (const int4*)dst;
    int4 dc[4];
    int rra[16];
#pragma unroll
    for (int q = 0; q < 4; ++q) {
        int v = vbase + q * 512 + tid;
        if (v < VEC_E) {
            int4 d = d4[v];
            dc[q] = d;
            rra[q * 4 + 0] = atomicAdd(&h[d.x >> 8], 1);
            rra[q * 4 + 1] = atomicAdd(&h[d.y >> 8], 1);
            rra[q * 4 + 2] = atomicAdd(&h[d.z >> 8], 1);
            rra[q * 4 + 3] = atomicAdd(&h[d.w >> 8], 1);
        }
    }
    __syncthreads();
    for (int i = tid; i < NB; i += 512) {
        int c = h[i];
        claim[i] = c ? atomicAdd(&cursor[i], c) : 0;
    }
    __syncthreads();
    const int4* s4 = (const int4*)src;
    const float4* w4 = (const float4*)w;
#pragma unroll
    for (int q = 0; q < 4; ++q) {
        int v = vbase + q * 512 + tid;
        if (v < VEC_E) {
            int4 d = dc[q];
            int4 s = s4[v];
            float4 ww = w4[v];
            int bin, dl, pos;
            bin = d.x >> 8; dl = d.x & 255; pos = claim[bin] + rra[q * 4 + 0];
            if (pos < CAPA) entries[(size_t)bin * CAPA + pos] = make_float2(__int_as_float(s.x | (dl << 17)), ww.x);
            bin = d.y >> 8; dl = d.y & 255; pos = claim[bin] + rra[q * 4 + 1];
            if (pos < CAPA) entries[(size_t)bin * CAPA + pos] = make_float2(__int_as_float(s.y | (dl << 17)), ww.y);
            bin = d.z >> 8; dl = d.z & 255; pos = claim[bin] + rra[q * 4 + 2];
            if (pos < CAPA) entries[(size_t)bin * CAPA + pos] = make_float2(__int_as_float(s.z | (dl << 17)), ww.z);
            bin = d.w >> 8; dl = d.w & 255; pos = claim[bin] + rra[q * 4 + 3];
            if (pos < CAPA) entries[(size_t)bin * CAPA + pos] = make_float2(__int_as_float(s.w | (dl << 17)), ww.w);
        }
    }
}

// Phase 2: fused degree + fp16 y per coarse bin; block 0 also derives gate
// params P (replaces the separate params launch).
__global__ void __launch_bounds__(1024)
prep_kernel(const float2* __restrict__ entries, const int* __restrict__ cursor,
            const float* __restrict__ x, float* __restrict__ dinv, __half* __restrict__ y,
            const float* __restrict__ wz, const float* __restrict__ bz,
            const float* __restrict__ wh, const float* __restrict__ bh,
            const float* __restrict__ lwz, const float* __restrict__ lbz,
            const float* __restrict__ lwh, const float* __restrict__ lbh,
            const float* __restrict__ att, float* __restrict__ P) {
    __shared__ float wsum[NODES_PER_B];
    __shared__ float dloc[NODES_PER_B];
    int tid = threadIdx.x;
    int b = blockIdx.x;
    int nbase = b << 8;
    size_t lo = (size_t)b * CAPA;
    int ne = cursor[b]; if (ne > CAPA) ne = CAPA;
    if (tid < NODES_PER_B) wsum[tid] = 0.f;
    __syncthreads();
    for (int k = tid; k < ne; k += 1024) {
        float2 e = entries[lo + k];
        atomicAdd(&wsum[(__float_as_int(e.x) >> 17) & 255], e.y);
    }
    __syncthreads();
    if (tid < NODES_PER_B) {
        int n = nbase + tid;
        float di = (n < N_NODES) ? rsqrtf(1.0f + wsum[tid]) : 0.f;
        dloc[tid] = di;
        if (n < N_NODES) dinv[n] = di;
    }
    __syncthreads();
    if (tid < 512) {
        int nl = tid >> 1, q = tid & 1;
        int n = nbase + nl;
        if (n < N_NODES) {
            float di = dloc[nl];
            union { __half h[8]; float4 f4; } u;
            if (q == 0) {
                float4 a = ((const float4*)x)[(size_t)n * 3 + 0];
                float4 c = ((const float4*)x)[(size_t)n * 3 + 1];
                u.h[0] = __float2half_rn(a.x * di); u.h[1] = __float2half_rn(a.y * di);
                u.h[2] = __float2half_rn(a.z * di); u.h[3] = __float2half_rn(a.w * di);
                u.h[4] = __float2half_rn(c.x * di); u.h[5] = __float2half_rn(c.y * di);
                u.h[6] = __float2half_rn(c.z * di); u.h[7] = __float2half_rn(c.w * di);
            } else {
                float4 c = ((const float4*)x)[(size_t)n * 3 + 2];
                u.h[0] = __float2half_rn(c.x * di); u.h[1] = __float2half_rn(c.y * di);
                u.h[2] = __float2half_rn(c.z * di); u.h[3] = __float2half_rn(c.w * di);
                u.h[4] = __ushort_as_half((unsigned short)0);
                u.h[5] = __ushort_as_half((unsigned short)0);
                u.h[6] = __ushort_as_half((unsigned short)0);
                u.h[7] = __ushort_as_half((unsigned short)0);
            }
            ((float4*)y)[((size_t)n << 1) + q] = u.f4;
        }
    }
    if (b == 0) {
        int o = tid;
        if (o < C_H) {
            float az = 0.f, bzv = 0.f, ah = 0.f, bhv = 0.f;
            for (int c = 0; c < C_H; ++c) {
                float lz = lwz[o * 2 * C_H + c];
                float lh = lwh[o * 2 * C_H + c];
                az += wz[c] * lz;  bzv += bz[c] * lz;
                ah += wh[c] * lh;  bhv += bh[c] * lh;
            }
            P[16 + o]  = az;  P[48 + o]  = bzv + lbz[o];
            P[80 + o]  = ah;  P[112 + o] = bhv + lbh[o];
        }
        if (o == 0) {
            float m = -1e30f;
            for (int t = 0; t < T_P; ++t) m = fmaxf(m, att[t]);
            float e[T_P], s = 0.f;
            for (int t = 0; t < T_P; ++t) { e[t] = __expf(att[t] - m); s += e[t]; }
            float inv = 1.0f / s;
            for (int t = 0; t < T_P; ++t) P[t] = e[t] * inv;
        }
    }
}

// Phase 3 (round-12 proven): per coarse bin (256 nodes): register-staged
// counting sort + 4-lane-per-node gather on the L2-resident fp16 y-table +
// gate/attention/head math.
__global__ void __launch_bounds__(1024, 8)
sort_gather_kernel(const float2* __restrict__ entries, const int* __restrict__ cursor,
                   const float* __restrict__ dinv, const __half* __restrict__ y,
                   const float* __restrict__ P, const float* __restrict__ head_w,
                   const float* __restrict__ head_b, float* __restrict__ out) {
    __shared__ float2 stage[CAPA];              // 69.6 KB, node-sorted edge records
    __shared__ int   cnt[NODES_PER_B];
    __shared__ int   inc[NODES_PER_B];          // inclusive prefix
    __shared__ float Ps[160];
    __shared__ float hws[C_H];
    int tid = threadIdx.x;
    int b = blockIdx.x;
    size_t lo = (size_t)b * CAPA;
    int ne = cursor[b]; if (ne > CAPA) ne = CAPA;
    if (tid < 160) Ps[tid] = P[tid];
    if (tid < C_H) hws[tid] = head_w[tid];
    if (tid < NODES_PER_B) cnt[tid] = 0;
    __syncthreads();
    float2 ent[9];
    int    rr[9];
#pragma unroll
    for (int i = 0; i < 9; ++i) {
        int k = tid + i * 1024;
        if (k < ne) {
            float2 e = entries[lo + k];
            ent[i] = e;
            rr[i] = atomicAdd(&cnt[(__float_as_int(e.x) >> 17) & 255], 1);
        }
    }
    __syncthreads();
    if (tid < NODES_PER_B) inc[tid] = cnt[tid];
    __syncthreads();
    for (int d = 1; d < NODES_PER_B; d <<= 1) {
        int t = (tid >= d && tid < NODES_PER_B) ? inc[tid - d] : 0;
        __syncthreads();
        if (tid < NODES_PER_B) inc[tid] += t;
        __syncthreads();
    }
#pragma unroll
    for (int i = 0; i < 9; ++i) {
        int k = tid + i * 1024;
        if (k < ne) {
            int dl = (__float_as_int(ent[i].x) >> 17) & 255;
            stage[inc[dl] - cnt[dl] + rr[i]] = ent[i];
        }
    }
    __syncthreads();
    // ---- gather: 4 lanes per node; edges from LDS, fp16 y rows from L2 ----
    int nl = tid >> 2, lane = tid & 3;
    int n = (b << 8) + nl;
    if (n >= N_NODES) return;                   // no barriers below
    int end = inc[nl];
    int start = end - cnt[nl];
    float4 a0 = make_float4(0.f, 0.f, 0.f, 0.f);
    float4 a1 = a0, a2 = a0;
    if (lane == 0) {                            // self term, added once
        const float4* yn = (const float4*)(y + ((size_t)n << 4));
        float4 r0 = yn[0], r1 = yn[1];
        const __half2* hp = (const __half2*)&r0;
        const __half2* hq = (const __half2*)&r1;
        float2 p0 = __half22float2(hp[0]), p1 = __half22float2(hp[1]);
        float2 p2 = __half22float2(hp[2]), p3 = __half22float2(hp[3]);
        float2 p4 = __half22float2(hq[0]), p5 = __half22float2(hq[1]);
        a0 = make_float4(p0.x, p0.y, p1.x, p1.y);
        a1 = make_float4(p2.x, p2.y, p3.x, p3.y);
        a2 = make_float4(p4.x, p4.y, p5.x, p5.y);
    }
    for (int j = start + lane; j < end; j += 4) {
        float2 e = stage[j];
        int s = __float_as_int(e.x) & 0x1FFFF;
        float c = e.y;
        const float4* ys = (const float4*)(y + ((size_t)s << 4));  // one 64B line
        float4 r0 = ys[0], r1 = ys[1];
        const __half2* hp = (const __half2*)&r0;
        const __half2* hq = (const __half2*)&r1;
        float2 p0 = __half22float2(hp[0]), p1 = __half22float2(hp[1]);
        float2 p2 = __half22float2(hp[2]), p3 = __half22float2(hp[3]);
        float2 p4 = __half22float2(hq[0]), p5 = __half22float2(hq[1]);
        a0.x += c * p0.x; a0.y += c * p0.y; a0.z += c * p1.x; a0.w += c * p1.y;
        a1.x += c * p2.x; a1.y += c * p2.y; a1.z += c * p3.x; a1.w += c * p3.y;
        a2.x += c * p4.x; a2.y += c * p4.y; a2.z += c * p5.x; a2.w += c * p5.y;
    }
#define RED4(v) v += __shfl_xor(v, 1); v += __shfl_xor(v, 2)
    RED4(a0.x); RED4(a0.y); RED4(a0.z); RED4(a0.w);
    RED4(a1.x); RED4(a1.y); RED4(a1.z); RED4(a1.w);
    RED4(a2.x); RED4(a2.y); RED4(a2.z); RED4(a2.w);
#undef RED4
    float din = dinv[n];
    float av[T_P];
    av[0] = a0.x * din; av[1] = a0.y * din; av[2]  = a0.z * din; av[3]  = a0.w * din;
    av[4] = a1.x * din; av[5] = a1.y * din; av[6]  = a1.z * din; av[7]  = a1.w * din;
    av[8] = a2.x * din; av[9] = a2.y * din; av[10] = a2.z * din; av[11] = a2.w * din;
    float acc = 0.f;
#pragma unroll
    for (int k = 0; k < 8; ++k) {
        int c = (lane << 3) + k;
        float Az = Ps[16 + c], Bz = Ps[48 + c], Ah = Ps[80 + c], Bh = Ps[112 + c];
        float hc = 0.f;
#pragma unroll
        for (int t = 0; t < T_P; ++t) {
            float a = av[t];
            float oz = 1.f / (1.f + __expf(a * Az + Bz));      // 1 - sigmoid(u)
            float vv = a * Ah + Bh;
            float th = 1.f - 2.f / (1.f + __expf(2.f * vv));   // tanh
            hc += Ps[t] * oz * th;
        }
        acc += fmaxf(hc, 0.f) * hws[c];
    }
    acc += __shfl_xor(acc, 1);
    acc += __shfl_xor(acc, 2);
    if (lane == 0) out[n] = acc + head_b[0];
}

extern "C" void kernel_launch(void* const* d_in, const int* in_sizes, int n_in,
                              void* d_out, int out_size, void* d_ws, size_t ws_size,
                              hipStream_t stream) {
    const float* x    = (const float*)d_in[0];
    const int*   ei   = (const int*)d_in[1];      // [2, E]: src = ei, dst = ei + E
    const float* ew   = (const float*)d_in[2];
    const float* w_z  = (const float*)d_in[3];
    const float* b_z  = (const float*)d_in[4];
    const float* w_h  = (const float*)d_in[7];
    const float* b_h  = (const float*)d_in[8];
    const float* lw_z = (const float*)d_in[9];
    const float* lb_z = (const float*)d_in[10];
    const float* lw_h = (const float*)d_in[13];
    const float* lb_h = (const float*)d_in[14];
    const float* att  = (const float*)d_in[15];
    const float* hw   = (const float*)d_in[16];
    const float* hb   = (const float*)d_in[17];
    float* out = (float*)d_out;

    float* wsf      = (float*)d_ws;
    float* P        = wsf;                          // 256           @0
    float* dinv     = P + 256;                      // N             @256
    int*   cursor   = (int*)(dinv + N_NODES);       // NB            @100256
    __half* y       = (__half*)(wsf + 100656);      // N*16 halves (32B rows)
    float2* entries = (float2*)(wsf + 100656 + (size_t)N_NODES * 8);  // NB*CAPA

    const int* srcp = ei;
    const int* dstp = ei + E_EDGES;

    hipMemsetAsync(cursor, 0, NB * sizeof(int), stream);
    bucket_scatter_kernel<<<NBLK1, P1_THREADS, 0, stream>>>(srcp, dstp, ew, cursor, entries);
    prep_kernel<<<NB, 1024, 0, stream>>>(entries, cursor, x, dinv, y,
                                         w_z, b_z, w_h, b_h, lw_z, lb_z, lw_h, lb_h, att, P);
    sort_gather_kernel<<<NB, 1024, 0, stream>>>(entries, cursor, dinv, y, P, hw, hb, out);
}